// Round 10
// baseline (439.126 us; speedup 1.0000x reference)
//
#include <hip/hip_runtime.h>
#include <hip/hip_cooperative_groups.h>
#include <math.h>
#include <stdint.h>

namespace cg = cooperative_groups;

#define BB 16
#define DD 96
#define TT 512
#define HH 1024
#define NROW (BB*DD)   // 1536

typedef __attribute__((ext_vector_type(4))) float floatx4;
typedef __attribute__((ext_vector_type(8))) short short8;

// ---------------- ws layout (bytes) ----------------
#define WSOFF_X     0                               // attn out fp32 3MB; reused as hfrag bf16 3MB
#define WSOFF_XROW  (3*1024*1024)                   // 1.5MB
#define WSOFF_XFRAG (WSOFF_XROW + NROW*TT*2)        // 1.5MB
#define WSOFF_W1BF  (WSOFF_XFRAG + NROW*TT*2)       // 1MB
#define WSOFF_W2BF  (WSOFF_W1BF + TT*HH*2)          // 1MB
#define WSOFF_A     (WSOFF_W2BF + HH*TT*2)          // 576KB
#define WSOFF_P1    (WSOFF_A + BB*DD*DD*4)
#define WSOFF_P2    (WSOFF_P1 + DD*128*4)
#define WSOFF_S     (WSOFF_P2 + DD*128*4)           // 1536 fp32 row sums

__device__ __forceinline__ uint16_t f2bf(float v) {
    uint32_t u = __float_as_uint(v);
    uint32_t r = 0x7fffu + ((u >> 16) & 1u);
    return (uint16_t)((u + r) >> 16);
}
__device__ __forceinline__ float bf2f(uint16_t v) {
    return __uint_as_float(((uint32_t)v) << 16);
}

#define KT1 (TT/32)    // 16
#define KT2 (HH/32)    // 32
__device__ __forceinline__ size_t afrag1_slot(int row, int k) {
    return ((size_t)((row >> 4)*KT1 + (k >> 5))*64 + ((k >> 3) & 3)*16 + (row & 15));
}

// Mega-kernel, 512 blocks x 256 threads. Runs phases [plo,phi]; grid.sync only
// when coop!=0. Fallback path launches it 7x with (p,p,0) — identical numerics.
__global__ __launch_bounds__(256, 4) void k_fused(
        int plo, int phi, int coop,
        const float* __restrict__ r,
        const float* __restrict__ bng, const float* __restrict__ bnb,
        const float* __restrict__ lng, const float* __restrict__ lnb,
        const float* __restrict__ W1,  const float* __restrict__ b1,
        const float* __restrict__ W2,  const float* __restrict__ b2,
        float* __restrict__ out,
        float* __restrict__ x, uint16_t* __restrict__ xrow,
        uint16_t* __restrict__ xfrag, uint16_t* __restrict__ w1bf,
        uint16_t* __restrict__ w2bf, float* __restrict__ A,
        float* __restrict__ P1, float* __restrict__ P2,
        float* __restrict__ s) {
    cg::grid_group grid = cg::this_grid();
    __shared__ __align__(16) float sbuf[DD*64];     // 24KB, aliased per phase
    uint16_t* hfrag = reinterpret_cast<uint16_t*>(x);   // x dead after phase 3
    int bx = blockIdx.x;
    int tid = threadIdx.x;
    int w = tid >> 6, lane = tid & 63;
    int q = lane >> 4, l15 = lane & 15;

    // ---- phase 0: row sums, 3 rows per block ----
    if (plo <= 0 && 0 <= phi) {
        #pragma unroll
        for (int p = 0; p < 3; ++p) {
            int row = bx + 512*p;
            float2 v = reinterpret_cast<const float2*>(r + (size_t)row*TT)[tid];
            float acc = v.x + v.y;
            #pragma unroll
            for (int o = 32; o > 0; o >>= 1) acc += __shfl_down(acc, o, 64);
            if (lane == 0) sbuf[w] = acc;
            __syncthreads();
            if (tid == 0) s[row] = sbuf[0]+sbuf[1]+sbuf[2]+sbuf[3];
            __syncthreads();
        }
    }
    if (coop) grid.sync();

    // ---- phase 1: softmax, one wave per row of A ----
    if (plo <= 1 && 1 <= phi) {
        int gw = bx*4 + w;
        if (gw < NROW) {
            int b = gw / DD, i = gw - b*DD;
            const float* sb = s + b*DD;
            const float c = 1.0f / (512.0f * 22.627416997969522f);  // T^-1.5
            float si = sb[i] * c;
            float v0 = si * sb[lane];
            float v1 = (lane < DD-64) ? si * sb[64 + lane] : -1e30f;
            float m = fmaxf(v0, v1);
            #pragma unroll
            for (int o = 32; o > 0; o >>= 1) m = fmaxf(m, __shfl_xor(m, o, 64));
            float e0 = expf(v0 - m);
            float e1 = (lane < DD-64) ? expf(v1 - m) : 0.f;
            float sum = e0 + e1;
            #pragma unroll
            for (int o = 32; o > 0; o >>= 1) sum += __shfl_xor(sum, o, 64);
            float inv = 1.0f / sum;
            float* Ao = A + (size_t)gw*DD;
            Ao[lane] = e0 * inv;
            if (lane < DD-64) Ao[64 + lane] = e1 * inv;
        }
    }
    if (coop) grid.sync();

    // ---- phase 2: wswiz (all blocks, 4 wave-chunks) then attn (all blocks) ----
    if (plo <= 2 && 2 <= phi) {
        {   // weight swizzle: 2048 wave-chunks = 512 blocks x 4 waves
            int blk = bx*4 + w;
            const float* W; uint16_t* outw; int KT, N, b;
            if (blk < 1024) { W = W1; outw = w1bf; KT = 16; N = 1024; b = blk; }
            else            { W = W2; outw = w2bf; KT = 32; N = 512;  b = blk - 1024; }
            int tile_n = b / KT, tile_k = b % KT;
            const float* src = W + (size_t)(tile_k*32 + q*8)*N + tile_n*16 + l15;
            uint16_t tmp[8];
            #pragma unroll
            for (int j = 0; j < 8; ++j) tmp[j] = f2bf(src[(size_t)j*N]);
            uint16_t* dst = outw + ((size_t)b*64 + lane)*8;
            *reinterpret_cast<ushort4*>(dst)     = *reinterpret_cast<ushort4*>(&tmp[0]);
            *reinterpret_cast<ushort4*>(dst + 4) = *reinterpret_cast<ushort4*>(&tmp[4]);
        }
        {   // attention unit bx: (b, chunk, ig)
            int b = bx & 15, chunk = (bx >> 4) & 7, ig = bx >> 7;
            int t0 = chunk * 64;
            const float4* rb4 = reinterpret_cast<const float4*>(r + (size_t)b*DD*TT);
            float4* rl4 = reinterpret_cast<float4*>(sbuf);
            #pragma unroll
            for (int ss = 0; ss < 6; ++ss) {
                int ii = tid + ss*256;
                rl4[ii] = rb4[(size_t)(ii >> 4)*(TT/4) + (t0 >> 2) + (ii & 15)];
            }
            __syncthreads();
            int wu = __builtin_amdgcn_readfirstlane(w);
            int i0 = ig*24 + wu*6;
            const float* Ab = A + ((size_t)b*DD + i0)*DD;
            float acc[6];
            #pragma unroll
            for (int rr = 0; rr < 6; ++rr) acc[rr] = sbuf[(i0+rr)*64 + lane];
            #pragma unroll 4
            for (int j4 = 0; j4 < DD/4; ++j4) {
                float4 a[6];
                #pragma unroll
                for (int rr = 0; rr < 6; ++rr)
                    a[rr] = *reinterpret_cast<const float4*>(Ab + rr*DD + j4*4);
                float rv[4];
                #pragma unroll
                for (int u = 0; u < 4; ++u) rv[u] = sbuf[(j4*4+u)*64 + lane];
                #pragma unroll
                for (int rr = 0; rr < 6; ++rr) {
                    acc[rr] = fmaf(a[rr].x, rv[0], acc[rr]);
                    acc[rr] = fmaf(a[rr].y, rv[1], acc[rr]);
                    acc[rr] = fmaf(a[rr].z, rv[2], acc[rr]);
                    acc[rr] = fmaf(a[rr].w, rv[3], acc[rr]);
                }
            }
            int p = b*8 + chunk;
            #pragma unroll
            for (int rr = 0; rr < 6; ++rr) {
                int i = i0 + rr;
                x[((size_t)b*DD + i)*TT + t0 + lane] = acc[rr];
                float ls = acc[rr], ls2 = acc[rr]*acc[rr];
                #pragma unroll
                for (int o = 32; o > 0; o >>= 1) {
                    ls  += __shfl_down(ls,  o, 64);
                    ls2 += __shfl_down(ls2, o, 64);
                }
                if (lane == 0) { P1[i*128 + p] = ls; P2[i*128 + p] = ls2; }
            }
            __syncthreads();
        }
    }
    if (coop) grid.sync();

    // ---- phase 3: BN finalize + cast; units 0..767, loop bx, bx+512 ----
    if (plo <= 3 && 3 <= phi) {
        for (int u = bx; u < 768; u += 512) {
            float* rr1 = sbuf; float* rr2 = sbuf + 4; float* scsh = sbuf + 8;
            int r0 = u*2;
            int d0 = r0 % DD, d1 = (r0+1) % DD;
            int d = (w < 2) ? d0 : d1;
            int p = (w & 1)*64 + lane;
            float v1 = P1[d*128 + p], v2 = P2[d*128 + p];
            #pragma unroll
            for (int o = 32; o > 0; o >>= 1) {
                v1 += __shfl_down(v1, o, 64);
                v2 += __shfl_down(v2, o, 64);
            }
            if (lane == 0) { rr1[w] = v1; rr2[w] = v2; }
            __syncthreads();
            if (tid < 2) {
                float s1 = rr1[tid*2] + rr1[tid*2+1];
                float s2 = rr2[tid*2] + rr2[tid*2+1];
                const float invn = 1.0f / (float)(BB*TT);
                float mu  = s1 * invn;
                float var = s2 * invn - mu*mu;
                float rs  = rsqrtf(var + 1e-5f);
                int dd = (tid == 0) ? d0 : d1;
                float scale = rs * bng[dd];
                scsh[tid*2]   = scale;
                scsh[tid*2+1] = bnb[dd] - mu*scale;
            }
            __syncthreads();
            int half = tid >> 7;
            int row = r0 + half;
            int k0 = (tid & 127) * 4;
            float scd = scsh[half*2], shd = scsh[half*2+1];
            float4 v = *reinterpret_cast<const float4*>(&x[(size_t)row*TT + k0]);
            ushort4 o;
            o.x = f2bf(v.x*scd + shd);
            o.y = f2bf(v.y*scd + shd);
            o.z = f2bf(v.z*scd + shd);
            o.w = f2bf(v.w*scd + shd);
            *reinterpret_cast<ushort4*>(&xrow[(size_t)row*TT + k0]) = o;
            size_t slot = afrag1_slot(row, k0);
            *reinterpret_cast<ushort4*>(&xfrag[slot*8 + (k0 & 7)]) = o;
            __syncthreads();
        }
    }
    if (coop) grid.sync();

    // ---- phase 4: gemm1 -> hfrag; units 0..767, loop bx, bx+512 ----
    if (plo <= 4 && 4 <= phi) {
        for (int u = bx; u < 768; u += 512) {
            uint16_t* cs = reinterpret_cast<uint16_t*>(sbuf);   // 16 x 136
            int mtile = u >> 3, ny = u & 7;
            int n0 = ny * 128 + w * 32;
            floatx4 acc[2] = {};
            const uint16_t* ap  = xfrag + ((size_t)mtile*KT1*64 + lane)*8;
            const uint16_t* b0p = w1bf + ((size_t)((n0>>4)    )*16*64 + lane)*8;
            const uint16_t* b1p = w1bf + ((size_t)((n0>>4) + 1)*16*64 + lane)*8;
            #pragma unroll
            for (int kk = 0; kk < 16; ++kk) {
                short8 a  = *reinterpret_cast<const short8*>(ap  + kk*512);
                short8 b0 = *reinterpret_cast<const short8*>(b0p + kk*512);
                short8 b1 = *reinterpret_cast<const short8*>(b1p + kk*512);
                acc[0] = __builtin_amdgcn_mfma_f32_16x16x32_bf16(a, b0, acc[0], 0, 0, 0);
                acc[1] = __builtin_amdgcn_mfma_f32_16x16x32_bf16(a, b1, acc[1], 0, 0, 0);
            }
            #pragma unroll
            for (int nf = 0; nf < 2; ++nf) {
                int coll = w*32 + nf*16 + l15;
                float bias = b1[ny*128 + coll];
                #pragma unroll
                for (int rr = 0; rr < 4; ++rr) {
                    float v = acc[nf][rr] + bias;
                    float gl = 0.5f * v * (1.0f + erff(v * 0.7071067811865475f));
                    cs[(q*4 + rr)*136 + coll] = f2bf(gl);
                }
            }
            __syncthreads();
            const uint4* src = reinterpret_cast<const uint4*>(&cs[l15*136 + w*32 + q*8]);
            size_t chunk = (size_t)mtile*KT2 + (ny*4 + w);
            reinterpret_cast<uint4*>(hfrag)[chunk*64 + lane] = *src;
            __syncthreads();
        }
    }
    if (coop) grid.sync();

    // ---- phase 5: gemm2 -> out; units 0..383 ----
    if (plo <= 5 && 5 <= phi) {
        if (bx < 384) {
            int mtile = bx >> 2, ny = bx & 3;
            int m0 = mtile * 16;
            int n0 = ny * 128 + w * 32;
            floatx4 acc[2] = {};
            const uint16_t* ap  = hfrag + ((size_t)mtile*KT2*64 + lane)*8;
            const uint16_t* b0p = w2bf + ((size_t)((n0>>4)    )*32*64 + lane)*8;
            const uint16_t* b1p = w2bf + ((size_t)((n0>>4) + 1)*32*64 + lane)*8;
            #pragma unroll
            for (int kk = 0; kk < 32; ++kk) {
                short8 a  = *reinterpret_cast<const short8*>(ap  + kk*512);
                short8 b0 = *reinterpret_cast<const short8*>(b0p + kk*512);
                short8 b1 = *reinterpret_cast<const short8*>(b1p + kk*512);
                acc[0] = __builtin_amdgcn_mfma_f32_16x16x32_bf16(a, b0, acc[0], 0, 0, 0);
                acc[1] = __builtin_amdgcn_mfma_f32_16x16x32_bf16(a, b1, acc[1], 0, 0, 0);
            }
            #pragma unroll
            for (int nf = 0; nf < 2; ++nf) {
                int col = n0 + nf*16 + l15;
                float bias = b2[col];
                #pragma unroll
                for (int rr = 0; rr < 4; ++rr) {
                    int row = m0 + q*4 + rr;
                    float xb = bf2f(xrow[(size_t)row*TT + col]);
                    out[(size_t)row*TT + col] = acc[nf][rr] + bias + xb;
                }
            }
        }
    }
    if (coop) grid.sync();

    // ---- phase 6: LayerNorm, one wave per row ----
    if (plo <= 6 && 6 <= phi) {
        int gw = bx*4 + w;
        if (gw < NROW) {
            float4* p = reinterpret_cast<float4*>(out + (size_t)gw*TT);
            float4 v0 = p[lane*2], v1 = p[lane*2 + 1];
            float sa = v0.x+v0.y+v0.z+v0.w + v1.x+v1.y+v1.z+v1.w;
            float s2 = v0.x*v0.x+v0.y*v0.y+v0.z*v0.z+v0.w*v0.w
                     + v1.x*v1.x+v1.y*v1.y+v1.z*v1.z+v1.w*v1.w;
            #pragma unroll
            for (int o = 1; o < 64; o <<= 1) {
                sa += __shfl_xor(sa, o, 64);
                s2 += __shfl_xor(s2, o, 64);
            }
            float mu = sa * (1.0f/TT);
            float var = s2 * (1.0f/TT) - mu*mu;
            float rs = rsqrtf(var + 1e-5f);
            const float4* g4 = reinterpret_cast<const float4*>(lng);
            const float4* b4 = reinterpret_cast<const float4*>(lnb);
            float4 g0 = g4[lane*2], g1 = g4[lane*2+1];
            float4 bb0 = b4[lane*2], bb1 = b4[lane*2+1];
            float4 o0, o1;
            o0.x = (v0.x-mu)*rs*g0.x + bb0.x;  o0.y = (v0.y-mu)*rs*g0.y + bb0.y;
            o0.z = (v0.z-mu)*rs*g0.z + bb0.z;  o0.w = (v0.w-mu)*rs*g0.w + bb0.w;
            o1.x = (v1.x-mu)*rs*g1.x + bb1.x;  o1.y = (v1.y-mu)*rs*g1.y + bb1.y;
            o1.z = (v1.z-mu)*rs*g1.z + bb1.z;  o1.w = (v1.w-mu)*rs*g1.w + bb1.w;
            p[lane*2] = o0;  p[lane*2+1] = o1;
        }
    }
}

extern "C" void kernel_launch(void* const* d_in, const int* in_sizes, int n_in,
                              void* d_out, int out_size, void* d_ws, size_t ws_size,
                              hipStream_t stream) {
    (void)in_sizes; (void)n_in; (void)out_size; (void)ws_size;
    const float* residual = (const float*)d_in[0];
    const float* bng = (const float*)d_in[1];
    const float* bnb = (const float*)d_in[2];
    const float* lng = (const float*)d_in[3];
    const float* lnb = (const float*)d_in[4];
    const float* W1  = (const float*)d_in[5];
    const float* b1  = (const float*)d_in[6];
    const float* W2  = (const float*)d_in[7];
    const float* b2  = (const float*)d_in[8];
    float* out = (float*)d_out;
    char* ws = (char*)d_ws;
    float*    x     = (float*)(ws + WSOFF_X);
    uint16_t* xrow  = (uint16_t*)(ws + WSOFF_XROW);
    uint16_t* xfrag = (uint16_t*)(ws + WSOFF_XFRAG);
    uint16_t* w1bf  = (uint16_t*)(ws + WSOFF_W1BF);
    uint16_t* w2bf  = (uint16_t*)(ws + WSOFF_W2BF);
    float*    A     = (float*)(ws + WSOFF_A);
    float*    P1    = (float*)(ws + WSOFF_P1);
    float*    P2    = (float*)(ws + WSOFF_P2);
    float*    s     = (float*)(ws + WSOFF_S);

    int plo = 0, phi = 6, coop = 1;
    void* args[] = { (void*)&plo, (void*)&phi, (void*)&coop,
                     (void*)&residual, (void*)&bng, (void*)&bnb, (void*)&lng,
                     (void*)&lnb, (void*)&W1, (void*)&b1, (void*)&W2, (void*)&b2,
                     (void*)&out, (void*)&x, (void*)&xrow, (void*)&xfrag,
                     (void*)&w1bf, (void*)&w2bf, (void*)&A, (void*)&P1,
                     (void*)&P2, (void*)&s };
    hipError_t rc = hipLaunchCooperativeKernel((const void*)k_fused, dim3(512),
                                               dim3(256), args, 0, stream);
    if (rc != hipSuccess) {
        // fallback: same kernel, one phase per ordinary dispatch (stream-ordered)
        for (int p = 0; p < 7; ++p) {
            k_fused<<<512, 256, 0, stream>>>(p, p, 0,
                residual, bng, bnb, lng, lnb, W1, b1, W2, b2, out,
                x, xrow, xfrag, w1bf, w2bf, A, P1, P2, s);
        }
    }
}

// Round 11
// 161.905 us; speedup vs baseline: 2.7122x; 2.7122x over previous
//
#include <hip/hip_runtime.h>
#include <math.h>
#include <stdint.h>

#define BB 16
#define DD 96
#define TT 512
#define HH 1024
#define NROW (BB*DD)   // 1536

typedef __attribute__((ext_vector_type(4))) float floatx4;
typedef __attribute__((ext_vector_type(8))) short short8;

// ---------------- ws layout (bytes) ----------------
#define WSOFF_X     0                               // attn out fp32 3MB; reused as hfrag bf16 3MB
#define WSOFF_XROW  (3*1024*1024)                   // 1.5MB
#define WSOFF_XFRAG (WSOFF_XROW + NROW*TT*2)        // 1.5MB
#define WSOFF_W1BF  (WSOFF_XFRAG + NROW*TT*2)       // 1MB
#define WSOFF_W2BF  (WSOFF_W1BF + TT*HH*2)          // 1MB
#define WSOFF_P1    (WSOFF_W2BF + HH*TT*2)          // 96*128 fp32
#define WSOFF_P2    (WSOFF_P1 + DD*128*4)
#define WSOFF_S     (WSOFF_P2 + DD*128*4)           // 1536 fp32 row sums
#define WSOFF_CNT   (WSOFF_S + NROW*4)              // 96 ints (LN semaphores)

__device__ __forceinline__ uint16_t f2bf(float v) {
    uint32_t u = __float_as_uint(v);
    uint32_t r = 0x7fffu + ((u >> 16) & 1u);
    return (uint16_t)((u + r) >> 16);
}
__device__ __forceinline__ float bf2f(uint16_t v) {
    return __uint_as_float(((uint32_t)v) << 16);
}

#define KT1 (TT/32)    // 16
#define KT2 (HH/32)    // 32
__device__ __forceinline__ size_t afrag1_slot(int row, int k) {
    return ((size_t)((row >> 4)*KT1 + (k >> 5))*64 + ((k >> 3) & 3)*16 + (row & 15));
}

// K1: row sums, 3 rows per block; block 0 also zeroes the LN semaphores.
__global__ __launch_bounds__(256) void k_rowsum(const float* __restrict__ r,
                                                float* __restrict__ s,
                                                int* __restrict__ cnt) {
    __shared__ float sbuf[4];
    int bx = blockIdx.x, tid = threadIdx.x;
    int w = tid >> 6, lane = tid & 63;
    if (bx == 0 && tid < DD) cnt[tid] = 0;
    #pragma unroll
    for (int p = 0; p < 3; ++p) {
        int row = bx + 512*p;
        float2 v = reinterpret_cast<const float2*>(r + (size_t)row*TT)[tid];
        float acc = v.x + v.y;
        #pragma unroll
        for (int o = 32; o > 0; o >>= 1) acc += __shfl_down(acc, o, 64);
        if (lane == 0) sbuf[w] = acc;
        __syncthreads();
        if (tid == 0) s[row] = sbuf[0]+sbuf[1]+sbuf[2]+sbuf[3];
        __syncthreads();
    }
}

// K2: [0,512): wswiz; [512,1024): attn with in-wave softmax + BN partials.
__global__ __launch_bounds__(256) void k_attw(const float* __restrict__ r,
                                              const float* __restrict__ s,
                                              const float* __restrict__ W1,
                                              const float* __restrict__ W2,
                                              float* __restrict__ x,
                                              uint16_t* __restrict__ w1bf,
                                              uint16_t* __restrict__ w2bf,
                                              float* __restrict__ P1,
                                              float* __restrict__ P2) {
    __shared__ __align__(16) float rlds[DD*64];   // 24KB
    __shared__ float sls[DD];
    __shared__ __align__(16) float Atile[24][DD]; // 9KB, wave-private rows
    int bx = blockIdx.x, tid = threadIdx.x;
    int w = tid >> 6, lane = tid & 63;
    int q = lane >> 4, l15 = lane & 15;
    if (bx < 512) {
        int blk = bx*4 + w;
        const float* W; uint16_t* outw; int KT, N, b;
        if (blk < 1024) { W = W1; outw = w1bf; KT = 16; N = 1024; b = blk; }
        else            { W = W2; outw = w2bf; KT = 32; N = 512;  b = blk - 1024; }
        int tile_n = b / KT, tile_k = b % KT;
        const float* src = W + (size_t)(tile_k*32 + q*8)*N + tile_n*16 + l15;
        uint16_t tmp[8];
        #pragma unroll
        for (int j = 0; j < 8; ++j) tmp[j] = f2bf(src[(size_t)j*N]);
        uint16_t* dst = outw + ((size_t)b*64 + lane)*8;
        *reinterpret_cast<ushort4*>(dst)     = *reinterpret_cast<ushort4*>(&tmp[0]);
        *reinterpret_cast<ushort4*>(dst + 4) = *reinterpret_cast<ushort4*>(&tmp[4]);
        return;
    }
    int idx = bx - 512;
    int b = idx & 15, chunk = (idx >> 4) & 7, ig = idx >> 7;
    int t0 = chunk * 64;
    const float4* rb4 = reinterpret_cast<const float4*>(r + (size_t)b*DD*TT);
    float4* rl4 = reinterpret_cast<float4*>(rlds);
    #pragma unroll
    for (int ss = 0; ss < 6; ++ss) {
        int ii = tid + ss*256;
        rl4[ii] = rb4[(size_t)(ii >> 4)*(TT/4) + (t0 >> 2) + (ii & 15)];
    }
    if (tid < DD) sls[tid] = s[b*DD + tid];
    __syncthreads();

    int wu = __builtin_amdgcn_readfirstlane(w);
    int i0 = ig*24 + wu*6;
    // in-wave softmax for this wave's 6 rows -> Atile (wave-private, no extra sync)
    const float c = 1.0f / (512.0f * 22.627416997969522f);  // T^-1.5
    float sl0 = sls[lane];
    float sl1 = (lane < DD-64) ? sls[64 + lane] : 0.f;
    #pragma unroll
    for (int rr = 0; rr < 6; ++rr) {
        float si = sls[i0+rr] * c;
        float v0 = si * sl0;
        float v1 = (lane < DD-64) ? si * sl1 : -1e30f;
        float m = fmaxf(v0, v1);
        #pragma unroll
        for (int o = 32; o > 0; o >>= 1) m = fmaxf(m, __shfl_xor(m, o, 64));
        float e0 = expf(v0 - m);
        float e1 = (lane < DD-64) ? expf(v1 - m) : 0.f;
        float sum = e0 + e1;
        #pragma unroll
        for (int o = 32; o > 0; o >>= 1) sum += __shfl_xor(sum, o, 64);
        float inv = 1.0f / sum;
        Atile[wu*6 + rr][lane] = e0 * inv;
        if (lane < DD-64) Atile[wu*6 + rr][64 + lane] = e1 * inv;
    }

    float acc[6];
    #pragma unroll
    for (int rr = 0; rr < 6; ++rr) acc[rr] = rlds[(i0+rr)*64 + lane];
    #pragma unroll 4
    for (int j4 = 0; j4 < DD/4; ++j4) {
        float4 a[6];
        #pragma unroll
        for (int rr = 0; rr < 6; ++rr)
            a[rr] = *reinterpret_cast<const float4*>(&Atile[wu*6 + rr][j4*4]);
        float rv[4];
        #pragma unroll
        for (int u = 0; u < 4; ++u) rv[u] = rlds[(j4*4+u)*64 + lane];
        #pragma unroll
        for (int rr = 0; rr < 6; ++rr) {
            acc[rr] = fmaf(a[rr].x, rv[0], acc[rr]);
            acc[rr] = fmaf(a[rr].y, rv[1], acc[rr]);
            acc[rr] = fmaf(a[rr].z, rv[2], acc[rr]);
            acc[rr] = fmaf(a[rr].w, rv[3], acc[rr]);
        }
    }
    int p = b*8 + chunk;
    #pragma unroll
    for (int rr = 0; rr < 6; ++rr) {
        int i = i0 + rr;
        x[((size_t)b*DD + i)*TT + t0 + lane] = acc[rr];
        float ls = acc[rr], ls2 = acc[rr]*acc[rr];
        #pragma unroll
        for (int o = 32; o > 0; o >>= 1) {
            ls  += __shfl_down(ls,  o, 64);
            ls2 += __shfl_down(ls2, o, 64);
        }
        if (lane == 0) { P1[i*128 + p] = ls; P2[i*128 + p] = ls2; }
    }
}

// K3: per 2 rows: reduce 128 partials -> BN affine; normalize + cast -> xrow, xfrag.
__global__ __launch_bounds__(256) void k_bnx(const float* __restrict__ x,
                                             const float* __restrict__ P1,
                                             const float* __restrict__ P2,
                                             const float* __restrict__ g,
                                             const float* __restrict__ bt,
                                             uint16_t* __restrict__ xrow,
                                             uint16_t* __restrict__ xfrag) {
    __shared__ float rr1[4], rr2[4], scsh[4];
    int blk = blockIdx.x, tid = threadIdx.x;
    int wid = tid >> 6, lane = tid & 63;
    int r0 = blk*2;
    int d0 = r0 % DD, d1 = (r0+1) % DD;
    int d = (wid < 2) ? d0 : d1;
    int p = (wid & 1)*64 + lane;
    float v1 = P1[d*128 + p], v2 = P2[d*128 + p];
    #pragma unroll
    for (int o = 32; o > 0; o >>= 1) {
        v1 += __shfl_down(v1, o, 64);
        v2 += __shfl_down(v2, o, 64);
    }
    if (lane == 0) { rr1[wid] = v1; rr2[wid] = v2; }
    __syncthreads();
    if (tid < 2) {
        float s1 = rr1[tid*2] + rr1[tid*2+1];
        float s2 = rr2[tid*2] + rr2[tid*2+1];
        const float invn = 1.0f / (float)(BB*TT);
        float mu  = s1 * invn;
        float var = s2 * invn - mu*mu;
        float rs  = rsqrtf(var + 1e-5f);
        int dd = (tid == 0) ? d0 : d1;
        float scale = rs * g[dd];
        scsh[tid*2]   = scale;
        scsh[tid*2+1] = bt[dd] - mu*scale;
    }
    __syncthreads();
    int half = tid >> 7;
    int row = r0 + half;
    int k0 = (tid & 127) * 4;
    float scd = scsh[half*2], shd = scsh[half*2+1];
    float4 v = *reinterpret_cast<const float4*>(&x[(size_t)row*TT + k0]);
    ushort4 o;
    o.x = f2bf(v.x*scd + shd);
    o.y = f2bf(v.y*scd + shd);
    o.z = f2bf(v.z*scd + shd);
    o.w = f2bf(v.w*scd + shd);
    *reinterpret_cast<ushort4*>(&xrow[(size_t)row*TT + k0]) = o;
    size_t slot = afrag1_slot(row, k0);
    *reinterpret_cast<ushort4*>(&xfrag[slot*8 + (k0 & 7)]) = o;
}

// K4: h = gelu(xn @ W1 + b1) in gemm2-A-frag order. grid (96, 8) x 256.
__global__ __launch_bounds__(256) void k_gemm1(const uint16_t* __restrict__ xfrag,
                                               const uint16_t* __restrict__ w1bf,
                                               const float* __restrict__ b1,
                                               uint16_t* __restrict__ hfrag) {
    __shared__ __align__(16) uint16_t cs[16][136];
    int tid = threadIdx.x;
    int wave = tid >> 6, lane = tid & 63;
    int q = lane >> 4, l15 = lane & 15;
    int mtile = blockIdx.x;
    int n0 = blockIdx.y * 128 + wave * 32;
    floatx4 acc[2] = {};
    const uint16_t* ap  = xfrag + ((size_t)mtile*KT1*64 + lane)*8;
    const uint16_t* b0p = w1bf + ((size_t)((n0>>4)    )*16*64 + lane)*8;
    const uint16_t* b1p = w1bf + ((size_t)((n0>>4) + 1)*16*64 + lane)*8;
    #pragma unroll
    for (int kk = 0; kk < 16; ++kk) {
        short8 a  = *reinterpret_cast<const short8*>(ap  + kk*512);
        short8 b0 = *reinterpret_cast<const short8*>(b0p + kk*512);
        short8 b1 = *reinterpret_cast<const short8*>(b1p + kk*512);
        acc[0] = __builtin_amdgcn_mfma_f32_16x16x32_bf16(a, b0, acc[0], 0, 0, 0);
        acc[1] = __builtin_amdgcn_mfma_f32_16x16x32_bf16(a, b1, acc[1], 0, 0, 0);
    }
    #pragma unroll
    for (int nf = 0; nf < 2; ++nf) {
        int coll = wave*32 + nf*16 + l15;
        float bias = b1[blockIdx.y*128 + coll];
        #pragma unroll
        for (int r = 0; r < 4; ++r) {
            float v = acc[nf][r] + bias;
            float gl = 0.5f * v * (1.0f + erff(v * 0.7071067811865475f));
            cs[q*4 + r][coll] = f2bf(gl);
        }
    }
    __syncthreads();
    int c = wave;
    const uint4* src = reinterpret_cast<const uint4*>(&cs[l15][c*32 + q*8]);
    size_t chunk = (size_t)mtile*KT2 + (blockIdx.y*4 + c);
    reinterpret_cast<uint4*>(hfrag)[chunk*64 + lane] = *src;
}

// K5: y = h @ W2 + b2 + xn -> out; last of the 4 n-blocks per mtile layernorms
// its 16 rows in-place (semaphore in cnt[], zeroed by k_rowsum).
__global__ __launch_bounds__(256) void k_gemm2ln(const uint16_t* __restrict__ hfrag,
                                                 const uint16_t* __restrict__ w2bf,
                                                 const float* __restrict__ b2,
                                                 const uint16_t* __restrict__ xrow,
                                                 const float* __restrict__ lng,
                                                 const float* __restrict__ lnb,
                                                 int* __restrict__ cnt,
                                                 float* __restrict__ y) {
    __shared__ int last;
    int tid = threadIdx.x;
    int wave = tid >> 6, lane = tid & 63;
    int q = lane >> 4, l15 = lane & 15;
    int mtile = blockIdx.x;
    int m0 = mtile * 16;
    int n0 = blockIdx.y * 128 + wave * 32;
    floatx4 acc[2] = {};
    const uint16_t* ap  = hfrag + ((size_t)mtile*KT2*64 + lane)*8;
    const uint16_t* b0p = w2bf + ((size_t)((n0>>4)    )*32*64 + lane)*8;
    const uint16_t* b1p = w2bf + ((size_t)((n0>>4) + 1)*32*64 + lane)*8;
    #pragma unroll
    for (int kk = 0; kk < 32; ++kk) {
        short8 a  = *reinterpret_cast<const short8*>(ap  + kk*512);
        short8 b0 = *reinterpret_cast<const short8*>(b0p + kk*512);
        short8 b1 = *reinterpret_cast<const short8*>(b1p + kk*512);
        acc[0] = __builtin_amdgcn_mfma_f32_16x16x32_bf16(a, b0, acc[0], 0, 0, 0);
        acc[1] = __builtin_amdgcn_mfma_f32_16x16x32_bf16(a, b1, acc[1], 0, 0, 0);
    }
    #pragma unroll
    for (int nf = 0; nf < 2; ++nf) {
        int col = n0 + nf*16 + l15;
        float bias = b2[col];
        #pragma unroll
        for (int r = 0; r < 4; ++r) {
            int row = m0 + q*4 + r;
            float xb = bf2f(xrow[(size_t)row*TT + col]);
            y[(size_t)row*TT + col] = acc[nf][r] + bias + xb;
        }
    }
    // --- LN handoff: last arriving n-block of this mtile does the 16 rows ---
    __threadfence();
    if (tid == 0) last = atomicAdd(&cnt[mtile], 1);
    __syncthreads();
    if (last != 3) return;
    __threadfence();
    #pragma unroll
    for (int rl = 0; rl < 4; ++rl) {
        int row = m0 + wave*4 + rl;
        float4* p = reinterpret_cast<float4*>(y + (size_t)row*TT);
        float4 v0 = p[lane*2], v1 = p[lane*2 + 1];
        float sa = v0.x+v0.y+v0.z+v0.w + v1.x+v1.y+v1.z+v1.w;
        float s2 = v0.x*v0.x+v0.y*v0.y+v0.z*v0.z+v0.w*v0.w
                 + v1.x*v1.x+v1.y*v1.y+v1.z*v1.z+v1.w*v1.w;
        #pragma unroll
        for (int o = 1; o < 64; o <<= 1) {
            sa += __shfl_xor(sa, o, 64);
            s2 += __shfl_xor(s2, o, 64);
        }
        float mu = sa * (1.0f/TT);
        float var = s2 * (1.0f/TT) - mu*mu;
        float rs = rsqrtf(var + 1e-5f);
        const float4* g4 = reinterpret_cast<const float4*>(lng);
        const float4* b4 = reinterpret_cast<const float4*>(lnb);
        float4 g0 = g4[lane*2], g1 = g4[lane*2+1];
        float4 bb0 = b4[lane*2], bb1 = b4[lane*2+1];
        float4 o0, o1;
        o0.x = (v0.x-mu)*rs*g0.x + bb0.x;  o0.y = (v0.y-mu)*rs*g0.y + bb0.y;
        o0.z = (v0.z-mu)*rs*g0.z + bb0.z;  o0.w = (v0.w-mu)*rs*g0.w + bb0.w;
        o1.x = (v1.x-mu)*rs*g1.x + bb1.x;  o1.y = (v1.y-mu)*rs*g1.y + bb1.y;
        o1.z = (v1.z-mu)*rs*g1.z + bb1.z;  o1.w = (v1.w-mu)*rs*g1.w + bb1.w;
        p[lane*2] = o0;  p[lane*2+1] = o1;
    }
}

extern "C" void kernel_launch(void* const* d_in, const int* in_sizes, int n_in,
                              void* d_out, int out_size, void* d_ws, size_t ws_size,
                              hipStream_t stream) {
    (void)in_sizes; (void)n_in; (void)out_size; (void)ws_size;
    const float* residual = (const float*)d_in[0];
    const float* bng = (const float*)d_in[1];
    const float* bnb = (const float*)d_in[2];
    const float* lng = (const float*)d_in[3];
    const float* lnb = (const float*)d_in[4];
    const float* W1  = (const float*)d_in[5];
    const float* b1  = (const float*)d_in[6];
    const float* W2  = (const float*)d_in[7];
    const float* b2  = (const float*)d_in[8];
    float* out = (float*)d_out;
    char* ws = (char*)d_ws;
    float*    x     = (float*)(ws + WSOFF_X);
    uint16_t* hfrag = (uint16_t*)(ws + WSOFF_X);       // aliases x; x dead after k_bnx
    uint16_t* xrow  = (uint16_t*)(ws + WSOFF_XROW);
    uint16_t* xfrag = (uint16_t*)(ws + WSOFF_XFRAG);
    uint16_t* w1bf  = (uint16_t*)(ws + WSOFF_W1BF);
    uint16_t* w2bf  = (uint16_t*)(ws + WSOFF_W2BF);
    float*    P1    = (float*)(ws + WSOFF_P1);
    float*    P2    = (float*)(ws + WSOFF_P2);
    float*    s     = (float*)(ws + WSOFF_S);
    int*      cnt   = (int*)(ws + WSOFF_CNT);

    k_rowsum<<<512, 256, 0, stream>>>(residual, s, cnt);
    k_attw<<<1024, 256, 0, stream>>>(residual, s, W1, W2, x, w1bf, w2bf, P1, P2);
    k_bnx<<<NROW/2, 256, 0, stream>>>(x, P1, P2, bng, bnb, xrow, xfrag);
    k_gemm1<<<dim3(96, 8), 256, 0, stream>>>(xfrag, w1bf, b1, hfrag);
    k_gemm2ln<<<dim3(96, 4), 256, 0, stream>>>(hfrag, w2bf, b2, xrow, lng, lnb, cnt, out);
}